// Round 9
// baseline (223.082 us; speedup 1.0000x reference)
//
#include <hip/hip_runtime.h>
#include <math.h>

#define D      256
#define BI     128     // rows per panel/block (8 m-tiles of 16)
#define NTHR   1024    // 16 waves: mg = wv&3 (2 m-tiles), jg = wv>>2 (16-j group)
#define KL     3       // per-stream top-k
#define NC     6       // refine candidates per row
#define STILE  64      // j per supertile (4 tiles of 16) = 32 KB fp16
#define BUFH   16384   // halfs per stage buffer (32 KB); 4 buffers = 128 KB
#define JSOFF  131072  // byte offset of j-side strip: 4 slots x 8 strips x 64 cols x 16B = 32 KB

// merge scratch layout: row stride 200 u32, 8 segments of 25 u32 (24 keys + 1 pad)
#define RSTR   200
#define SEGS   25
#define SMEMB  163840  // 128K stage + 32K strip = full 160 KB; merge scratch aliases stage

typedef _Float16 half8 __attribute__((ext_vector_type(8)));
typedef float f32x4 __attribute__((ext_vector_type(4)));
typedef __attribute__((address_space(3))) unsigned int lds_u32;
typedef const __attribute__((address_space(1))) unsigned int glb_u32;

#define WAITCNT_VM0  0xF70   // vmcnt(0)

#if __has_builtin(__builtin_amdgcn_sched_barrier)
#define SCHED_FENCE() __builtin_amdgcn_sched_barrier(0)
#else
#define SCHED_FENCE()
#endif

__device__ inline unsigned med3u(unsigned a, unsigned b, unsigned c) {
  unsigned d;
  asm("v_med3_u32 %0, %1, %2, %3" : "=v"(d) : "v"(a), "v"(b), "v"(c));
  return d;
}
__device__ inline unsigned uminu(unsigned a, unsigned b) { return a < b ? a : b; }
__device__ inline unsigned umaxu(unsigned a, unsigned b) { return a > b ? a : b; }

// sorted-ascending top-3 insert (min domain), 3 branchless ops
__device__ inline void ins3r(unsigned v, unsigned& t0, unsigned& t1, unsigned& t2) {
  const unsigned a = t0, b = t1;
  t0 = uminu(v, a);
  t1 = med3u(v, a, b);
  t2 = med3u(v, b, t2);
}

// merge sorted triple (b0<=b1<=b2) into sorted (a0<=a1<=a2): top-3 of union, 6 ops
__device__ inline void mrg3(unsigned b0, unsigned b1, unsigned b2,
                            unsigned& a0, unsigned& a1, unsigned& a2) {
  const unsigned v = uminu(a1, b1);
  const unsigned w = uminu(a2, b2);
  const unsigned u = umaxu(a0, b0);
  const unsigned t1 = med3u(a0, b0, v);
  a0 = uminu(a0, b0);
  a1 = t1;
  a2 = med3u(u, v, w);
}

// ---- fused prep (proven): per-row fp64 norm + invn + fp16 pack (tile order) ----
__global__ __launch_bounds__(256) void prep_kernel(const float* __restrict__ x,
    double* __restrict__ fen64, float* __restrict__ invn,
    _Float16* __restrict__ xBs, int n) {
  const int T   = blockIdx.x;
  const int tid = threadIdx.x;
  const int r   = tid >> 4;
  const int t   = tid & 15;
  const int row = T * 16 + r;

  float4 v[4];
  const float* sp = x + (size_t)row * D + t * 16;
  #pragma unroll
  for (int q = 0; q < 4; ++q) v[q] = *reinterpret_cast<const float4*>(sp + q * 4);

  double s = 0.0;
  #pragma unroll
  for (int q = 0; q < 4; ++q)
    s += (double)v[q].x * v[q].x + (double)v[q].y * v[q].y +
         (double)v[q].z * v[q].z + (double)v[q].w * v[q].w;
  s += __shfl_down(s, 8); s += __shfl_down(s, 4);
  s += __shfl_down(s, 2); s += __shfl_down(s, 1);

  __shared__ float sInv[16];
  if (t == 0) {
    const double f = sqrt(s + D * 1e-6);
    fen64[row] = f;
    const float iv = (float)(1.0 / f);
    invn[row] = iv;
    sInv[r] = iv;
  }
  __syncthreads();
  const float inv = sInv[r];

  const int kc  = t >> 1;
  const int hi0 = (t & 1) * 2;
  half8 h0, h1;
  h0[0] = (_Float16)(v[0].x * inv); h0[1] = (_Float16)(v[0].y * inv);
  h0[2] = (_Float16)(v[0].z * inv); h0[3] = (_Float16)(v[0].w * inv);
  h0[4] = (_Float16)(v[1].x * inv); h0[5] = (_Float16)(v[1].y * inv);
  h0[6] = (_Float16)(v[1].z * inv); h0[7] = (_Float16)(v[1].w * inv);
  h1[0] = (_Float16)(v[2].x * inv); h1[1] = (_Float16)(v[2].y * inv);
  h1[2] = (_Float16)(v[2].z * inv); h1[3] = (_Float16)(v[2].w * inv);
  h1[4] = (_Float16)(v[3].x * inv); h1[5] = (_Float16)(v[3].y * inv);
  h1[6] = (_Float16)(v[3].z * inv); h1[7] = (_Float16)(v[3].w * inv);
  _Float16* base = xBs + (size_t)T * 4096;
  *reinterpret_cast<half8*>(base + kc * 512 + (hi0 * 16 + r) * 8) = h0;
  *reinterpret_cast<half8*>(base + kc * 512 + ((hi0 + 1) * 16 + r) * 8) = h1;
}

// min-domain insert-6: b[0..5] sorted ascending
__device__ inline void ins6(unsigned int v, unsigned int* b) {
  if (v < b[5]) {
    bool g0 = v < b[0], g1 = v < b[1], g2 = v < b[2], g3 = v < b[3], g4 = v < b[4];
    unsigned int o0 = b[0], o1 = b[1], o2 = b[2], o3 = b[3], o4 = b[4];
    b[5] = g4 ? o4 : v;             b[4] = g4 ? (g3 ? o3 : v) : o4;
    b[3] = g3 ? (g2 ? o2 : v) : o3; b[2] = g2 ? (g1 ? o1 : v) : o2;
    b[1] = g1 ? (g0 ? o0 : v) : o1; b[0] = g0 ? v : o0;
  }
}

// ---- main: symmetric tournament sweep, XCD-grouped ----
// vs R8 (isolating A/B): (1) NO s_setprio — in a barrier-locked 16-wave block
// prio1-during-MFMA starves the other 3 waves/SIMD and serializes compute
// windows (guide m190: setprio is negative on lockstep GEMM structures);
// (2) flush moved AFTER compute(t),compute(t+1) — same barrier interval
// protects strip-slot reuse, but flush waves now reach their MFMAs with the
// pack and the strip merge overlaps other waves' compute tails.
__global__ __launch_bounds__(NTHR, 4) void neighbors_kernel(
    const _Float16* __restrict__ xBs, unsigned int* __restrict__ candG,
    unsigned int* __restrict__ candI, int n) {
  extern __shared__ char smem[];
  _Float16* sB = (_Float16*)smem;                   // 4 x BUFH halfs (128 KB)
  unsigned int* cand = (unsigned int*)smem;         // merge scratch aliases stage
  const int tid  = threadIdx.x;
  const int lane = tid & 63;
  const int wv   = tid >> 6;
  const int mg   = wv & 3;    // m-wave-group: 2 m-tiles of 16 (32 rows)
  const int jg   = wv >> 2;   // j-subtile (16 j) within 64-j supertile
  const int nIdx = lane & 15;
  const int quad = lane >> 4;
  const int bid  = blockIdx.x;
  const int P    = n / BI;              // 128 panels
  const int x8   = bid & 7;             // XCD (de-facto round-robin)
  const int k    = bid >> 3;            // 0..31 within XCD
  const int ch   = k & 1;               // sweep chunk
  const int r16  = k >> 1;              // 0..15
  const int p    = x8 * 16 + r16;       // this block's i-panel
  const int d0   = ch ? 33 : 0;
  const int dE   = ch ? (p < P / 2 ? P / 2 + 1 : P / 2) : 33;   // exclusive
  const int L    = dE - d0;             // d-values this block covers
  const int NSW  = 2 * L;               // supertiles (even)
  const int i0   = p * BI;

  // A fragments: 2 m-tiles x 8 k-chunks from swizzled xBs (layout == B-frags)
  half8 afrag[2][8];
  #pragma unroll
  for (int mt = 0; mt < 2; ++mt) {
    const _Float16* ap = xBs + (size_t)(i0 / 16 + 2 * mg + mt) * 4096 + lane * 8;
    #pragma unroll
    for (int kc = 0; kc < 8; ++kc)
      afrag[mt][kc] = *reinterpret_cast<const half8*>(ap + kc * 512);
  }

  unsigned int tk[8][KL];
  #pragma unroll
  for (int e = 0; e < 8; ++e)
    #pragma unroll
    for (int c = 0; c < KL; ++c) tk[e][c] = 0xFFFFFFFFu;

  // hoisted per-lane constants
  const unsigned jl = (unsigned)(jg * 16 + nIdx);        // i-side key low bits (lane part)
  unsigned ibk[8];                                       // j-side key low bits (global i)
  #pragma unroll
  for (int mt = 0; mt < 2; ++mt)
    #pragma unroll
    for (int r = 0; r < 4; ++r)
      ibk[mt * 4 + r] = (unsigned)(i0 + (2 * mg + mt) * 16 + quad * 4 + r);

  auto dma_tile = [&](int d, int t, int bufI) {
    const int q = (p + d) & (P - 1);
    const int tile0 = q * 8 + (t & 1) * 4;
    const _Float16* src = xBs + (size_t)tile0 * 4096 + wv * 1024 + lane * 8;
    _Float16* dst = sB + (size_t)bufI * BUFH + wv * 1024;
    #pragma unroll
    for (int c = 0; c < 2; ++c)
      __builtin_amdgcn_global_load_lds((glb_u32*)(src + c * 512),
                                       (lds_u32*)(dst + c * 512), 16, 0, 0);
  };

  auto compute = [&](int d, int t) {
    const int q = (p + d) & (P - 1);
    const int bi = t & 3;
    f32x4 acc0 = {-1.f, -1.f, -1.f, -1.f};   // acc = cos - 1 (<=0 except self)
    f32x4 acc1 = {-1.f, -1.f, -1.f, -1.f};
    const _Float16* bb = sB + (size_t)bi * BUFH + jg * 4096 + lane * 8;
    #pragma unroll
    for (int kc = 0; kc < 8; ++kc) {
      const half8 bf = *reinterpret_cast<const half8*>(bb + kc * 512);
      acc0 = __builtin_amdgcn_mfma_f32_16x16x32_f16(afrag[0][kc], bf, acc0, 0, 0, 0);
      acc1 = __builtin_amdgcn_mfma_f32_16x16x32_f16(afrag[1][kc], bf, acc1, 0, 0, 0);
    }
    const unsigned ju = (unsigned)(q * BI + (t & 1) * STILE) | jl;
    unsigned s0 = 0xFFFFFFFFu, s1 = 0xFFFFFFFFu, s2 = 0xFFFFFFFFu;
    #pragma unroll
    for (int mt = 0; mt < 2; ++mt) {
      #pragma unroll
      for (int r = 0; r < 4; ++r) {
        const float s = (mt == 0) ? acc0[r] : acc1[r];
        const int e = mt * 4 + r;
        const unsigned m = __float_as_uint(s) & 0xFFFFC000u;
        ins3r(m | ju, tk[e][0], tk[e][1], tk[e][2]);     // i-side
        ins3r(m | ibk[e], s0, s1, s2);                   // j-side (lane-local column)
      }
    }
    if (d > 0) {           // one butterfly stage: quad pairs {0,1}, {2,3}
      const unsigned b0 = __shfl_xor(s0, 16);
      const unsigned b1 = __shfl_xor(s1, 16);
      const unsigned b2 = __shfl_xor(s2, 16);
      mrg3(b0, b1, b2, s0, s1, s2);
      if ((quad & 1) == 0) {
        uint4* jb = (uint4*)(smem + JSOFF)
                    + (size_t)(bi * 8 + mg * 2 + (quad >> 1)) * 64 + (jg * 16 + nIdx);
        *jb = make_uint4(s0, s1, s2, s2);
      }
    }
  };

  // flush supertile tp's strip (8 half-merged triples per col) -> candG[d-1][rows]
  auto flush1 = [&](int d, int tp) {
    if (tp < 0 || d == 0) return;
    const int sl = tp & 3;
    const uint4* jb = (const uint4*)(smem + JSOFF) + (size_t)sl * 8 * 64 + lane;
    uint4 t0 = jb[0];
    unsigned a0 = t0.x, a1 = t0.y, a2 = t0.z;
    #pragma unroll
    for (int m = 1; m < 8; ++m) {
      const uint4 tm = jb[(size_t)m * 64];
      mrg3(tm.x, tm.y, tm.z, a0, a1, a2);
    }
    const int q = (p + d) & (P - 1);
    const int rowg = q * BI + (tp & 1) * STILE + lane;
    unsigned* dst = candG + ((size_t)(d - 1) * n + rowg) * 3;
    dst[0] = a0; dst[1] = a1; dst[2] = a2;
  };

  // d-ring: Dm = pair(t-2), Dc = pair(t), Dn = pair(t+2); increment-wrap, no modulo
  const int dstart = d0 + (r16 ? (L - r16) : 0);
  auto nxt = [&](int d) { return (d + 1 >= dE) ? d0 : d + 1; };
  int Dm = 0, Dc = dstart, Dn = nxt(dstart);

  dma_tile(Dc, 0, 0);
  dma_tile(Dc, 1, 1);
  for (int t = 0; t < NSW; t += 2) {
    __builtin_amdgcn_s_waitcnt(WAITCNT_VM0);
    __builtin_amdgcn_s_barrier();
    SCHED_FENCE();
    if (t + 2 < NSW) dma_tile(Dn, t + 2, (t + 2) & 3);
    if (t + 3 < NSW) dma_tile(Dn, t + 3, (t + 3) & 3);
    compute(Dc, t);
    compute(Dc, t + 1);
    if (wv == 0) flush1(Dm, t - 2);            // after computes: overlaps other
    else if (wv == 4) flush1(Dm, t - 1);       // waves' compute tails
    Dm = Dc; Dc = Dn; Dn = nxt(Dn);
  }
  __syncthreads();   // last deposits visible; stage area dead
  if (wv == 0) flush1(Dm, NSW - 2);
  else if (wv == 4) flush1(Dm, NSW - 1);

  // i-side deposit: row from verified 16x16 C/D mapping
  #pragma unroll
  for (int mt = 0; mt < 2; ++mt) {
    #pragma unroll
    for (int r = 0; r < 4; ++r) {
      const int row  = (2 * mg + mt) * 16 + quad * 4 + r;
      const int slot = jg * 16 + nIdx;
      const int base = row * RSTR + slot * KL + (slot >> 3);
      #pragma unroll
      for (int c = 0; c < KL; ++c) cand[base + c] = tk[mt * 4 + r][c];
    }
  }
  __syncthreads();

  // stage-A: 8 threads/row reduce 24 candidates to top-6 in place
  {
    const int row = tid >> 3, seg = tid & 7, base = row * RSTR + seg * SEGS;
    unsigned int best[NC];
    #pragma unroll
    for (int c = 0; c < NC; ++c) best[c] = 0xFFFFFFFFu;
    for (int k2 = 0; k2 < 24; ++k2) ins6(cand[base + k2], best);
    #pragma unroll
    for (int c = 0; c < NC; ++c) cand[base + c] = best[c];
  }
  __syncthreads();

  // stage-B: one thread/row -> top-6 i-side keys to candI[row][ch*6..]
  if (tid < BI) {
    unsigned int best[NC];
    #pragma unroll
    for (int c = 0; c < NC; ++c) best[c] = 0xFFFFFFFFu;
    for (int seg = 0; seg < 8; ++seg)
      for (int c = 0; c < NC; ++c) ins6(cand[tid * RSTR + seg * SEGS + c], best);
    unsigned int* outp = candI + (size_t)(i0 + tid) * 12 + ch * 6;
    #pragma unroll
    for (int c = 0; c < NC; ++c) outp[c] = best[c];
  }
}

// ---- finalize: global candidate merge + fp64 refine + weights + gather ----
__global__ __launch_bounds__(512) void finalize_kernel(
    const float* __restrict__ x, const unsigned int* __restrict__ candG,
    const unsigned int* __restrict__ candI,
    const double* __restrict__ fen64, float* __restrict__ out, int n) {
  __shared__ unsigned m6[32][16][NC];   // 12 KB per-seg top-6
  __shared__ int    sel[32][NC];
  __shared__ double s64[32][NC];
  __shared__ float  wOut[32][3];
  __shared__ int    iOut[32][3];
  const int tid = threadIdx.x;
  const int base = blockIdx.x * 32;

  {  // per-seg scan, coalesced: r = tid&31 (consecutive rows), seg = tid>>5
    const int r = tid & 31, seg = tid >> 5;
    const int row = base + r;
    const int pnl = row >> 7;              // row / BI
    unsigned best[NC];
    #pragma unroll
    for (int c = 0; c < NC; ++c) best[c] = 0xFFFFFFFFu;
    #pragma unroll
    for (int ss = 0; ss < 4; ++ss) {
      const int dslot = seg + ss * 16;     // 0..63
      if (dslot == 63 && pnl < (n / BI / 2)) continue;   // unwritten slot
      const unsigned* cp = candG + ((size_t)dslot * n + row) * 3;
      ins6(cp[0], best); ins6(cp[1], best); ins6(cp[2], best);
    }
    if (seg < 2) {                         // i-side: 6 keys per chunk
      const unsigned* cp = candI + (size_t)row * 12 + seg * 6;
      #pragma unroll
      for (int k2 = 0; k2 < 6; ++k2) ins6(cp[k2], best);
    }
    #pragma unroll
    for (int c = 0; c < NC; ++c) m6[r][seg][c] = best[c];
  }
  __syncthreads();

  if (tid < 32) {                       // merge 16 segs -> top-6
    unsigned best[NC];
    #pragma unroll
    for (int c = 0; c < NC; ++c) best[c] = 0xFFFFFFFFu;
    for (int sg = 0; sg < 16; ++sg)
      #pragma unroll
      for (int c = 0; c < NC; ++c) ins6(m6[tid][sg][c], best);
    #pragma unroll
    for (int c = 0; c < NC; ++c) sel[tid][c] = (int)(best[c] & 0x3FFFu);
  }
  __syncthreads();

  if (tid < 32 * NC * 2) {              // fp64 refine: 2 threads per dot
    const int r  = tid / (NC * 2);
    const int c2 = tid % (NC * 2);
    const int c  = c2 >> 1;
    const int hf = c2 & 1;
    const int j  = sel[r][c];
    const float* xi = x + (size_t)(base + r) * D + hf * 128;
    const float* xj = x + (size_t)j * D + hf * 128;
    double a0 = 0, a1 = 0, a2 = 0, a3 = 0;
    for (int d = 0; d < 128; d += 4) {
      float4 va = *reinterpret_cast<const float4*>(xi + d);
      float4 vb = *reinterpret_cast<const float4*>(xj + d);
      a0 += (double)va.x * vb.x; a1 += (double)va.y * vb.y;
      a2 += (double)va.z * vb.z; a3 += (double)va.w * vb.w;
    }
    double half_dot = (a0 + a1) + (a2 + a3);
    const double other = __shfl_xor(half_dot, 1);
    if (hf == 0)
      s64[r][c] = (half_dot + other) / (fen64[base + r] * fen64[j]);
  }
  __syncthreads();

  if (tid < 32) {
    double sv0 = s64[tid][0], sv1 = s64[tid][1], sv2 = s64[tid][2],
           sv3 = s64[tid][3], sv4 = s64[tid][4], sv5 = s64[tid][5];
    int si0 = sel[tid][0], si1 = sel[tid][1], si2 = sel[tid][2],
        si3 = sel[tid][3], si4 = sel[tid][4], si5 = sel[tid][5];
#define CSW(a, b) { bool t_ = (sv##b > sv##a) || (sv##b == sv##a && si##b < si##a); \
    double d_ = t_ ? sv##b : sv##a; double e_ = t_ ? sv##a : sv##b; sv##a = d_; sv##b = e_; \
    int f_ = t_ ? si##b : si##a; int g_ = t_ ? si##a : si##b; si##a = f_; si##b = g_; }
    CSW(0,1) CSW(2,3) CSW(4,5) CSW(1,2) CSW(3,4)
    CSW(0,1) CSW(2,3) CSW(4,5) CSW(1,2) CSW(3,4)
    CSW(0,1) CSW(2,3) CSW(4,5) CSW(1,2) CSW(3,4)
#undef CSW
    const double Nn = (double)n;
    const double Zval = 1.0 + exp(-1.0) * (Nn - 1.0) * (1.0 + 1.0 / 512.0);
    const double mm = sv0;
    const double Zstar = Zval * exp(1.0 - mm);
    const double q0 = exp(sv0 - mm) / Zstar;
    const double q1 = exp(sv1 - mm) / Zstar;
    const double q2 = exp(sv2 - mm) / Zstar;
    const double e0 = exp(q0), e1 = exp(q1), e2 = exp(q2);
    const double S = e0 + e1 + e2;
    wOut[tid][0] = (float)(e0 / S); iOut[tid][0] = si0;
    wOut[tid][1] = (float)(e1 / S); iOut[tid][1] = si1;
    wOut[tid][2] = (float)(e2 / S); iOut[tid][2] = si2;
  }
  __syncthreads();

  {  // gather + weighted sum: 16 threads/row x 16 floats
    const int r = tid >> 4, seg = tid & 15;
    const float w0 = wOut[r][0], w1 = wOut[r][1], w2 = wOut[r][2];
    const float* x0 = x + (size_t)iOut[r][0] * D;
    const float* x1 = x + (size_t)iOut[r][1] * D;
    const float* x2 = x + (size_t)iOut[r][2] * D;
    float* op = out + (size_t)(base + r) * D;
    #pragma unroll
    for (int d4 = 0; d4 < 4; ++d4) {
      const int d = seg * 16 + d4 * 4;
      float4 A = *reinterpret_cast<const float4*>(x0 + d);
      float4 B = *reinterpret_cast<const float4*>(x1 + d);
      float4 C = *reinterpret_cast<const float4*>(x2 + d);
      float4 o;
      o.x = w0 * A.x + w1 * B.x + w2 * C.x;
      o.y = w0 * A.y + w1 * B.y + w2 * C.y;
      o.z = w0 * A.z + w1 * B.z + w2 * C.z;
      o.w = w0 * A.w + w1 * B.w + w2 * C.w;
      *reinterpret_cast<float4*>(op + d) = o;
    }
  }
}

extern "C" void kernel_launch(void* const* d_in, const int* in_sizes, int n_in,
                              void* d_out, int out_size, void* d_ws, size_t ws_size,
                              hipStream_t stream) {
  const float* x = (const float*)d_in[0];
  const int n = in_sizes[0] / D;                        // 16384
  _Float16* xBs = (_Float16*)d_ws;                      // n*D fp16 swizzled (8 MB)
  double* fen64 = (double*)(xBs + (size_t)n * D);       // n fp64
  float*  invn  = (float*)(fen64 + n);                  // n fp32
  unsigned int* candG = (unsigned int*)(invn + n);      // 64*n*3 u32 (12.6 MB)
  unsigned int* candI = candG + (size_t)64 * n * 3;     // n*12 u32 (768 KB)
  float*  out   = (float*)d_out;

  (void)hipFuncSetAttribute((const void*)neighbors_kernel,
                            hipFuncAttributeMaxDynamicSharedMemorySize, SMEMB);

  hipLaunchKernelGGL(prep_kernel, dim3(n / 16), dim3(256), 0, stream,
                     x, fen64, invn, xBs, n);
  hipLaunchKernelGGL(neighbors_kernel, dim3((n / BI) * 2), dim3(NTHR), SMEMB, stream,
                     xBs, candG, candI, n);
  hipLaunchKernelGGL(finalize_kernel, dim3(n / 32), dim3(512), 0, stream,
                     x, candG, candI, fen64, out, n);
}

// Round 11
// 210.230 us; speedup vs baseline: 1.0611x; 1.0611x over previous
//
#include <hip/hip_runtime.h>
#include <math.h>

#define D      256
#define BI     128     // rows per panel/block (8 m-tiles of 16)
#define NTHR   512     // 8 waves: mg = wv&3 (2 m-tiles), jg = wv>>2 (2 j-groups)
#define KL     3       // per-stream top-k
#define NC     6       // refine candidates per row
#define STILE  32      // j per supertile (2 tiles of 16) = 16 KB fp16
#define BUFH   8192    // halfs per stage buffer (16 KB); 4 buffers = 64 KB
#define JSOFF  65536   // j-side strip: 4 slots x 8 strips x 32 cols x 16B = 16 KB

// merge scratch: 96 keys/row in 8 segs of 12 (padded 13): row stride 104 u32
#define RSTR   104
#define SEGS   13
#define SMEMB  81920   // 64K stage + 16K strip = 80 KB -> 2 blocks/CU (160 KB exact)

typedef _Float16 half8 __attribute__((ext_vector_type(8)));
typedef float f32x4 __attribute__((ext_vector_type(4)));
typedef __attribute__((address_space(3))) unsigned int lds_u32;
typedef const __attribute__((address_space(1))) unsigned int glb_u32;

#define WAITCNT_VM0  0xF70   // vmcnt(0)

#if __has_builtin(__builtin_amdgcn_sched_barrier)
#define SCHED_FENCE() __builtin_amdgcn_sched_barrier(0)
#else
#define SCHED_FENCE()
#endif

__device__ inline unsigned med3u(unsigned a, unsigned b, unsigned c) {
  unsigned d;
  asm("v_med3_u32 %0, %1, %2, %3" : "=v"(d) : "v"(a), "v"(b), "v"(c));
  return d;
}
__device__ inline unsigned uminu(unsigned a, unsigned b) { return a < b ? a : b; }
__device__ inline unsigned umaxu(unsigned a, unsigned b) { return a > b ? a : b; }

// sorted-ascending top-3 insert (min domain), 3 branchless ops
__device__ inline void ins3r(unsigned v, unsigned& t0, unsigned& t1, unsigned& t2) {
  const unsigned a = t0, b = t1;
  t0 = uminu(v, a);
  t1 = med3u(v, a, b);
  t2 = med3u(v, b, t2);
}

// merge sorted triple (b0<=b1<=b2) into sorted (a0<=a1<=a2): top-3 of union, 6 ops
__device__ inline void mrg3(unsigned b0, unsigned b1, unsigned b2,
                            unsigned& a0, unsigned& a1, unsigned& a2) {
  const unsigned v = uminu(a1, b1);
  const unsigned w = uminu(a2, b2);
  const unsigned u = umaxu(a0, b0);
  const unsigned t1 = med3u(a0, b0, v);
  a0 = uminu(a0, b0);
  a1 = t1;
  a2 = med3u(u, v, w);
}

// ---- fused prep (proven): per-row fp64 norm + invn + fp16 pack (tile order) ----
__global__ __launch_bounds__(256) void prep_kernel(const float* __restrict__ x,
    double* __restrict__ fen64, float* __restrict__ invn,
    _Float16* __restrict__ xBs, int n) {
  const int T   = blockIdx.x;
  const int tid = threadIdx.x;
  const int r   = tid >> 4;
  const int t   = tid & 15;
  const int row = T * 16 + r;

  float4 v[4];
  const float* sp = x + (size_t)row * D + t * 16;
  #pragma unroll
  for (int q = 0; q < 4; ++q) v[q] = *reinterpret_cast<const float4*>(sp + q * 4);

  double s = 0.0;
  #pragma unroll
  for (int q = 0; q < 4; ++q)
    s += (double)v[q].x * v[q].x + (double)v[q].y * v[q].y +
         (double)v[q].z * v[q].z + (double)v[q].w * v[q].w;
  s += __shfl_down(s, 8); s += __shfl_down(s, 4);
  s += __shfl_down(s, 2); s += __shfl_down(s, 1);

  __shared__ float sInv[16];
  if (t == 0) {
    const double f = sqrt(s + D * 1e-6);
    fen64[row] = f;
    const float iv = (float)(1.0 / f);
    invn[row] = iv;
    sInv[r] = iv;
  }
  __syncthreads();
  const float inv = sInv[r];

  const int kc  = t >> 1;
  const int hi0 = (t & 1) * 2;
  half8 h0, h1;
  h0[0] = (_Float16)(v[0].x * inv); h0[1] = (_Float16)(v[0].y * inv);
  h0[2] = (_Float16)(v[0].z * inv); h0[3] = (_Float16)(v[0].w * inv);
  h0[4] = (_Float16)(v[1].x * inv); h0[5] = (_Float16)(v[1].y * inv);
  h0[6] = (_Float16)(v[1].z * inv); h0[7] = (_Float16)(v[1].w * inv);
  h1[0] = (_Float16)(v[2].x * inv); h1[1] = (_Float16)(v[2].y * inv);
  h1[2] = (_Float16)(v[2].z * inv); h1[3] = (_Float16)(v[2].w * inv);
  h1[4] = (_Float16)(v[3].x * inv); h1[5] = (_Float16)(v[3].y * inv);
  h1[6] = (_Float16)(v[3].z * inv); h1[7] = (_Float16)(v[3].w * inv);
  _Float16* base = xBs + (size_t)T * 4096;
  *reinterpret_cast<half8*>(base + kc * 512 + (hi0 * 16 + r) * 8) = h0;
  *reinterpret_cast<half8*>(base + kc * 512 + ((hi0 + 1) * 16 + r) * 8) = h1;
}

// min-domain insert-6: b[0..5] sorted ascending
__device__ inline void ins6(unsigned int v, unsigned int* b) {
  if (v < b[5]) {
    bool g0 = v < b[0], g1 = v < b[1], g2 = v < b[2], g3 = v < b[3], g4 = v < b[4];
    unsigned int o0 = b[0], o1 = b[1], o2 = b[2], o3 = b[3], o4 = b[4];
    b[5] = g4 ? o4 : v;             b[4] = g4 ? (g3 ? o3 : v) : o4;
    b[3] = g3 ? (g2 ? o2 : v) : o3; b[2] = g2 ? (g1 ? o1 : v) : o2;
    b[1] = g1 ? (g0 ? o0 : v) : o1; b[0] = g0 ? v : o0;
  }
}

// ---- main: symmetric tournament sweep, XCD-grouped, TWO blocks/CU ----
// 512-thread blocks (8 waves) with 80 KB LDS -> 2 independent barrier domains
// per CU (16 waves/CU, 4/SIMD unchanged).  When one block stalls at its
// barrier/flush, the co-resident block's waves fill the SIMDs -- attacks the
// ~50% idle that survived every pipe-load reduction (R4/R5/R8 nulls).
// Supertile = 32 j (2 tiles); each (panel,ch) sweep splits into 2 sub-ranges;
// co-resident pair: same XCD, same (ch,sub) cohort -> shared B-panel sequence.
// setprio kept (R9 A/B: removing it cost 10%); flush before computes (R8 order).
__global__ __launch_bounds__(NTHR, 4) void neighbors_kernel(
    const _Float16* __restrict__ xBs, unsigned int* __restrict__ candG,
    unsigned int* __restrict__ candI, int n) {
  extern __shared__ char smem[];
  _Float16* sB = (_Float16*)smem;                   // 4 x BUFH halfs (64 KB)
  unsigned int* cand = (unsigned int*)smem;         // merge scratch aliases stage
  const int tid  = threadIdx.x;
  const int lane = tid & 63;
  const int wv   = tid >> 6;  // 0..7
  const int mg   = wv & 3;    // m-wave-group: 2 m-tiles of 16 (32 rows)
  const int jg   = wv >> 2;   // j-subtile (16 j) within 32-j supertile
  const int nIdx = lane & 15;
  const int quad = lane >> 4;
  const int bid  = blockIdx.x;
  const int P    = n / BI;              // 128 panels
  const int x8   = bid & 7;             // XCD (de-facto round-robin)
  const int k    = bid >> 3;            // 0..63 within XCD
  const int ch   = k & 1;               // chunk
  const int sub  = (k >> 1) & 1;        // sub-range
  const int r16  = k >> 2;              // 0..15
  const int p    = x8 * 16 + r16;       // this block's i-panel
  const int i0   = p * BI;

  // d-range [d0s, d0s+Ls) for this (ch, sub)
  int d0s, Ls;
  if (ch == 0) { d0s = sub ? 17 : 0; Ls = sub ? 16 : 17; }
  else {
    const int dEe = (p < P / 2) ? (P / 2 + 1) : (P / 2);
    d0s = sub ? 49 : 33;
    Ls  = sub ? (dEe - 49) : 16;
  }
  const int dEs = d0s + Ls;
  const int NSW = 4 * Ls;               // 32-j supertiles (4 per d)

  // A fragments: 2 m-tiles x 8 k-chunks from swizzled xBs (layout == B-frags)
  half8 afrag[2][8];
  #pragma unroll
  for (int mt = 0; mt < 2; ++mt) {
    const _Float16* ap = xBs + (size_t)(i0 / 16 + 2 * mg + mt) * 4096 + lane * 8;
    #pragma unroll
    for (int kc = 0; kc < 8; ++kc)
      afrag[mt][kc] = *reinterpret_cast<const half8*>(ap + kc * 512);
  }

  unsigned int tk[8][KL];
  #pragma unroll
  for (int e = 0; e < 8; ++e)
    #pragma unroll
    for (int c = 0; c < KL; ++c) tk[e][c] = 0xFFFFFFFFu;

  // hoisted per-lane constants
  const unsigned jl = (unsigned)(jg * 16 + nIdx);   // i-side key low bits [0,32)
  unsigned ibk[8];                                  // j-side key low bits (global i)
  #pragma unroll
  for (int mt = 0; mt < 2; ++mt)
    #pragma unroll
    for (int r = 0; r < 4; ++r)
      ibk[mt * 4 + r] = (unsigned)(i0 + (2 * mg + mt) * 16 + quad * 4 + r);

  auto dma_tile = [&](int d, int t, int bufI) {
    const int q = (p + d) & (P - 1);
    const int tile0 = q * 8 + (t & 3) * 2;          // 2 tiles per 32-j supertile
    const _Float16* src = xBs + (size_t)tile0 * 4096 + wv * 1024 + lane * 8;
    _Float16* dst = sB + (size_t)bufI * BUFH + wv * 1024;
    #pragma unroll
    for (int c = 0; c < 2; ++c)
      __builtin_amdgcn_global_load_lds((glb_u32*)(src + c * 512),
                                       (lds_u32*)(dst + c * 512), 16, 0, 0);
  };

  auto compute = [&](int d, int t) {
    const int q = (p + d) & (P - 1);
    const int bi = t & 3;
    f32x4 acc0 = {-1.f, -1.f, -1.f, -1.f};   // acc = cos - 1 (<=0 except self)
    f32x4 acc1 = {-1.f, -1.f, -1.f, -1.f};
    const _Float16* bb = sB + (size_t)bi * BUFH + jg * 4096 + lane * 8;
    __builtin_amdgcn_s_setprio(1);            // proven needed (R9 A/B: -10% without)
    #pragma unroll
    for (int kc = 0; kc < 8; ++kc) {
      const half8 bf = *reinterpret_cast<const half8*>(bb + kc * 512);
      acc0 = __builtin_amdgcn_mfma_f32_16x16x32_f16(afrag[0][kc], bf, acc0, 0, 0, 0);
      acc1 = __builtin_amdgcn_mfma_f32_16x16x32_f16(afrag[1][kc], bf, acc1, 0, 0, 0);
    }
    __builtin_amdgcn_s_setprio(0);
    const unsigned ju = (unsigned)(q * BI + (t & 3) * STILE) | jl;
    unsigned s0 = 0xFFFFFFFFu, s1 = 0xFFFFFFFFu, s2 = 0xFFFFFFFFu;
    #pragma unroll
    for (int mt = 0; mt < 2; ++mt) {
      #pragma unroll
      for (int r = 0; r < 4; ++r) {
        const float s = (mt == 0) ? acc0[r] : acc1[r];
        const int e = mt * 4 + r;
        const unsigned m = __float_as_uint(s) & 0xFFFFC000u;
        ins3r(m | ju, tk[e][0], tk[e][1], tk[e][2]);     // i-side
        ins3r(m | ibk[e], s0, s1, s2);                   // j-side (lane-local column)
      }
    }
    if (d > 0) {           // one butterfly stage: quad pairs {0,1}, {2,3}
      const unsigned b0 = __shfl_xor(s0, 16);
      const unsigned b1 = __shfl_xor(s1, 16);
      const unsigned b2 = __shfl_xor(s2, 16);
      mrg3(b0, b1, b2, s0, s1, s2);
      if ((quad & 1) == 0) {
        uint4* jb = (uint4*)(smem + JSOFF)
                    + ((size_t)bi * 8 + mg * 2 + (quad >> 1)) * 32 + (jg * 16 + nIdx);
        *jb = make_uint4(s0, s1, s2, s2);
      }
    }
  };

  // flush supertile tp's strip (8 strips x 32 cols) -> candG[d-1][rows]
  auto flush1 = [&](int d, int tp) {
    if (tp < 0 || d == 0) return;
    const int sl  = tp & 3;
    const int col = lane & 31;
    const int sh  = lane >> 5;          // strip half: 0 -> strips 0..3, 1 -> 4..7
    const uint4* jb = (const uint4*)(smem + JSOFF)
                      + ((size_t)sl * 8 + sh * 4) * 32 + col;
    uint4 t0 = jb[0];
    unsigned a0 = t0.x, a1 = t0.y, a2 = t0.z;
    #pragma unroll
    for (int m = 1; m < 4; ++m) {
      const uint4 tm = jb[(size_t)m * 32];
      mrg3(tm.x, tm.y, tm.z, a0, a1, a2);
    }
    const unsigned b0 = __shfl_xor(a0, 32);   // cross half-merge
    const unsigned b1 = __shfl_xor(a1, 32);
    const unsigned b2 = __shfl_xor(a2, 32);
    mrg3(b0, b1, b2, a0, a1, a2);
    if (sh == 0) {
      const int q = (p + d) & (P - 1);
      const int rowg = q * BI + (tp & 3) * STILE + col;
      unsigned* dst = candG + ((size_t)(d - 1) * n + rowg) * 3;
      dst[0] = a0; dst[1] = a1; dst[2] = a2;
    }
  };

  // rotated d-sequence (XCD panel alignment), increment-wrap, no per-iter modulo
  const int rot = r16 % Ls;
  const int dstart = d0s + (rot ? (Ls - rot) : 0);
  auto nxt = [&](int d) { return (d + 1 >= dEs) ? d0s : d + 1; };
  int Dprev = 0, Dc = dstart;

  dma_tile(Dc, 0, 0);
  dma_tile(Dc, 1, 1);
  for (int t = 0; t < NSW; t += 2) {
    __builtin_amdgcn_s_waitcnt(WAITCNT_VM0);
    __builtin_amdgcn_s_barrier();
    SCHED_FENCE();
    const int half = (t >> 1) & 1;      // d advances every 4 supertiles
    const int pd = half ? nxt(Dc) : Dc; // d of supertiles t+2, t+3
    if (t + 2 < NSW) dma_tile(pd, t + 2, (t + 2) & 3);
    if (t + 3 < NSW) dma_tile(pd, t + 3, (t + 3) & 3);
    const int fd = half ? Dc : Dprev;   // d of supertiles t-2, t-1
    if (wv == 0) flush1(fd, t - 2);
    else if (wv == 4) flush1(fd, t - 1);
    compute(Dc, t);
    compute(Dc, t + 1);
    if (half) { Dprev = Dc; Dc = nxt(Dc); }
  }
  __syncthreads();   // last deposits visible; stage area dead
  if (wv == 0) flush1(Dprev, NSW - 2);
  else if (wv == 4) flush1(Dprev, NSW - 1);

  // i-side deposit: row from verified 16x16 C/D mapping; 32 slots x 3 per row,
  // 12-key segs padded to 13: addr = row*104 + slot*3 + (slot>>2)
  #pragma unroll
  for (int mt = 0; mt < 2; ++mt) {
    #pragma unroll
    for (int r = 0; r < 4; ++r) {
      const int row  = (2 * mg + mt) * 16 + quad * 4 + r;
      const int slot = jg * 16 + nIdx;
      const int base = row * RSTR + slot * KL + (slot >> 2);
      #pragma unroll
      for (int c = 0; c < KL; ++c) cand[base + c] = tk[mt * 4 + r][c];
    }
  }
  __syncthreads();

  // stage-A: 4 threads/row x 2 segs: reduce 12 keys -> top-6 in place
  {
    const int row = tid >> 2, sg2 = tid & 3;
    #pragma unroll
    for (int rr = 0; rr < 2; ++rr) {
      const int seg = sg2 * 2 + rr;
      const int base = row * RSTR + seg * SEGS;
      unsigned int best[NC];
      #pragma unroll
      for (int c = 0; c < NC; ++c) best[c] = 0xFFFFFFFFu;
      for (int k2 = 0; k2 < 12; ++k2) ins6(cand[base + k2], best);
      #pragma unroll
      for (int c = 0; c < NC; ++c) cand[base + c] = best[c];
    }
  }
  __syncthreads();

  // stage-B: one thread/row -> top-6 i-side keys to candI[row][g*6..], g=ch*2+sub
  if (tid < BI) {
    unsigned int best[NC];
    #pragma unroll
    for (int c = 0; c < NC; ++c) best[c] = 0xFFFFFFFFu;
    for (int seg = 0; seg < 8; ++seg)
      for (int c = 0; c < NC; ++c) ins6(cand[tid * RSTR + seg * SEGS + c], best);
    unsigned int* outp = candI + (size_t)(i0 + tid) * 24 + (ch * 2 + sub) * 6;
    #pragma unroll
    for (int c = 0; c < NC; ++c) outp[c] = best[c];
  }
}

// ---- finalize: global candidate merge + fp64 refine + weights + gather ----
__global__ __launch_bounds__(512) void finalize_kernel(
    const float* __restrict__ x, const unsigned int* __restrict__ candG,
    const unsigned int* __restrict__ candI,
    const double* __restrict__ fen64, float* __restrict__ out, int n) {
  __shared__ unsigned m6[32][16][NC];   // 12 KB per-seg top-6
  __shared__ int    sel[32][NC];
  __shared__ double s64[32][NC];
  __shared__ float  wOut[32][3];
  __shared__ int    iOut[32][3];
  const int tid = threadIdx.x;
  const int base = blockIdx.x * 32;

  {  // per-seg scan, coalesced: r = tid&31 (consecutive rows), seg = tid>>5
    const int r = tid & 31, seg = tid >> 5;
    const int row = base + r;
    const int pnl = row >> 7;              // row / BI
    unsigned best[NC];
    #pragma unroll
    for (int c = 0; c < NC; ++c) best[c] = 0xFFFFFFFFu;
    #pragma unroll
    for (int ss = 0; ss < 4; ++ss) {
      const int dslot = seg + ss * 16;     // 0..63
      if (dslot == 63 && pnl < (n / BI / 2)) continue;   // unwritten slot
      const unsigned* cp = candG + ((size_t)dslot * n + row) * 3;
      ins6(cp[0], best); ins6(cp[1], best); ins6(cp[2], best);
    }
    if (seg < 4) {                         // i-side: 6 keys per (ch,sub) group
      const unsigned* cp = candI + (size_t)row * 24 + seg * 6;
      #pragma unroll
      for (int k2 = 0; k2 < 6; ++k2) ins6(cp[k2], best);
    }
    #pragma unroll
    for (int c = 0; c < NC; ++c) m6[r][seg][c] = best[c];
  }
  __syncthreads();

  if (tid < 32) {                       // merge 16 segs -> top-6
    unsigned best[NC];
    #pragma unroll
    for (int c = 0; c < NC; ++c) best[c] = 0xFFFFFFFFu;
    for (int sg = 0; sg < 16; ++sg)
      #pragma unroll
      for (int c = 0; c < NC; ++c) ins6(m6[tid][sg][c], best);
    #pragma unroll
    for (int c = 0; c < NC; ++c) sel[tid][c] = (int)(best[c] & 0x3FFFu);
  }
  __syncthreads();

  if (tid < 32 * NC * 2) {              // fp64 refine: 2 threads per dot
    const int r  = tid / (NC * 2);
    const int c2 = tid % (NC * 2);
    const int c  = c2 >> 1;
    const int hf = c2 & 1;
    const int j  = sel[r][c];
    const float* xi = x + (size_t)(base + r) * D + hf * 128;
    const float* xj = x + (size_t)j * D + hf * 128;
    double a0 = 0, a1 = 0, a2 = 0, a3 = 0;
    for (int d = 0; d < 128; d += 4) {
      float4 va = *reinterpret_cast<const float4*>(xi + d);
      float4 vb = *reinterpret_cast<const float4*>(xj + d);
      a0 += (double)va.x * vb.x; a1 += (double)va.y * vb.y;
      a2 += (double)va.z * vb.z; a3 += (double)va.w * vb.w;
    }
    double half_dot = (a0 + a1) + (a2 + a3);
    const double other = __shfl_xor(half_dot, 1);
    if (hf == 0)
      s64[r][c] = (half_dot + other) / (fen64[base + r] * fen64[j]);
  }
  __syncthreads();

  if (tid < 32) {
    double sv0 = s64[tid][0], sv1 = s64[tid][1], sv2 = s64[tid][2],
           sv3 = s64[tid][3], sv4 = s64[tid][4], sv5 = s64[tid][5];
    int si0 = sel[tid][0], si1 = sel[tid][1], si2 = sel[tid][2],
        si3 = sel[tid][3], si4 = sel[tid][4], si5 = sel[tid][5];
#define CSW(a, b) { bool t_ = (sv##b > sv##a) || (sv##b == sv##a && si##b < si##a); \
    double d_ = t_ ? sv##b : sv##a; double e_ = t_ ? sv##a : sv##b; sv##a = d_; sv##b = e_; \
    int f_ = t_ ? si##b : si##a; int g_ = t_ ? si##a : si##b; si##a = f_; si##b = g_; }
    CSW(0,1) CSW(2,3) CSW(4,5) CSW(1,2) CSW(3,4)
    CSW(0,1) CSW(2,3) CSW(4,5) CSW(1,2) CSW(3,4)
    CSW(0,1) CSW(2,3) CSW(4,5) CSW(1,2) CSW(3,4)
#undef CSW
    const double Nn = (double)n;
    const double Zval = 1.0 + exp(-1.0) * (Nn - 1.0) * (1.0 + 1.0 / 512.0);
    const double mm = sv0;
    const double Zstar = Zval * exp(1.0 - mm);
    const double q0 = exp(sv0 - mm) / Zstar;
    const double q1 = exp(sv1 - mm) / Zstar;
    const double q2 = exp(sv2 - mm) / Zstar;
    const double e0 = exp(q0), e1 = exp(q1), e2 = exp(q2);
    const double S = e0 + e1 + e2;
    wOut[tid][0] = (float)(e0 / S); iOut[tid][0] = si0;
    wOut[tid][1] = (float)(e1 / S); iOut[tid][1] = si1;
    wOut[tid][2] = (float)(e2 / S); iOut[tid][2] = si2;
  }
  __syncthreads();

  {  // gather + weighted sum: 16 threads/row x 16 floats
    const int r = tid >> 4, seg = tid & 15;
    const float w0 = wOut[r][0], w1 = wOut[r][1], w2 = wOut[r][2];
    const float* x0 = x + (size_t)iOut[r][0] * D;
    const float* x1 = x + (size_t)iOut[r][1] * D;
    const float* x2 = x + (size_t)iOut[r][2] * D;
    float* op = out + (size_t)(base + r) * D;
    #pragma unroll
    for (int d4 = 0; d4 < 4; ++d4) {
      const int d = seg * 16 + d4 * 4;
      float4 A = *reinterpret_cast<const float4*>(x0 + d);
      float4 B = *reinterpret_cast<const float4*>(x1 + d);
      float4 C = *reinterpret_cast<const float4*>(x2 + d);
      float4 o;
      o.x = w0 * A.x + w1 * B.x + w2 * C.x;
      o.y = w0 * A.y + w1 * B.y + w2 * C.y;
      o.z = w0 * A.z + w1 * B.z + w2 * C.z;
      o.w = w0 * A.w + w1 * B.w + w2 * C.w;
      *reinterpret_cast<float4*>(op + d) = o;
    }
  }
}

extern "C" void kernel_launch(void* const* d_in, const int* in_sizes, int n_in,
                              void* d_out, int out_size, void* d_ws, size_t ws_size,
                              hipStream_t stream) {
  const float* x = (const float*)d_in[0];
  const int n = in_sizes[0] / D;                        // 16384
  _Float16* xBs = (_Float16*)d_ws;                      // n*D fp16 swizzled (8 MB)
  double* fen64 = (double*)(xBs + (size_t)n * D);       // n fp64
  float*  invn  = (float*)(fen64 + n);                  // n fp32
  unsigned int* candG = (unsigned int*)(invn + n);      // 64*n*3 u32 (12.6 MB)
  unsigned int* candI = candG + (size_t)64 * n * 3;     // n*24 u32 (1.5 MB)
  float*  out   = (float*)d_out;

  (void)hipFuncSetAttribute((const void*)neighbors_kernel,
                            hipFuncAttributeMaxDynamicSharedMemorySize, SMEMB);

  hipLaunchKernelGGL(prep_kernel, dim3(n / 16), dim3(256), 0, stream,
                     x, fen64, invn, xBs, n);
  hipLaunchKernelGGL(neighbors_kernel, dim3((n / BI) * 4), dim3(NTHR), SMEMB, stream,
                     xBs, candG, candI, n);
  hipLaunchKernelGGL(finalize_kernel, dim3(n / 32), dim3(512), 0, stream,
                     x, candG, candI, fen64, out, n);
}